// Round 2
// baseline (1159.221 us; speedup 1.0000x reference)
//
#include <hip/hip_runtime.h>

// NeuralBPDecoder: sparse BP over a 0.1%-dense parity matrix.
// Round 8: P2 restructured around REGISTER-RESIDENT CSR indices.
// Round-7 post-mortem showed the scan was never the hog; P2's per-batch
// chain (idx load -> wait -> 4 gathers -> wait) serialized two IF round
// trips per 4 edges, ~10us/iteration. The indices are loop-invariant, so
// they are now preloaded ONCE into packed-u64 VGPRs (12 row + 2x8 col
// batches, tails replaced by a DUMMY index into a zeroed 128B pad so no
// per-element masking is needed). Phases issue all gathers back-to-back
// from registers -> ~1 IF round trip per phase. Scan is hand-pipelined
// (rotate: next iteration's float4 loads issue before the branchy ballot
// compaction of the current one). Barrier scheme (relaxed-only, IF-coherent
// sc1 traffic) unchanged from round 7.

#define C_NUM 8192
#define V_NUM 16384
#define B_NUM 32
#define RW 64   // storage slots per check row (mean nnz 16.4)
#define CW 32   // storage slots per var col  (mean nnz  8.2)

#define RQ 12   // register u64 batches per row: 48 idx (max row nnz ~33)
#define CQ 8    // register u64 batches per col: 32 idx (max col nnz ~20)

#define NBLK 256
#define NTHR 1024
#define NTH (NBLK * NTHR)   // 262144 threads, 16 waves/CU

#define WCAP 256            // LDS edge slots per wave (mean 32.8, >30 sigma safe)

typedef unsigned short u16;
typedef unsigned int u32;
typedef unsigned long long u64;

#define ZERO_WORDS ((C_NUM * 4 + V_NUM * 4 + C_NUM * RW * 2 + V_NUM * CW * 2) / 4)
#define NBAR 31
#define BAR_STRIDE 64              // u32s between counters (256 B)

__device__ __forceinline__ float agent_ldf(const float* p) {
    return __hip_atomic_load(p, __ATOMIC_RELAXED, __HIP_MEMORY_SCOPE_AGENT);
}
__device__ __forceinline__ void agent_stf(float* p, float v) {
    __hip_atomic_store(p, v, __ATOMIC_RELAXED, __HIP_MEMORY_SCOPE_AGENT);
}
__device__ __forceinline__ u64 agent_ld64(const u64* p) {
    return __hip_atomic_load(p, __ATOMIC_RELAXED, __HIP_MEMORY_SCOPE_AGENT);
}
__device__ __forceinline__ int agent_ldi(const int* p) {
    return __hip_atomic_load(p, __ATOMIC_RELAXED, __HIP_MEMORY_SCOPE_AGENT);
}
__device__ __forceinline__ void agent_st32(u32* p, u32 v) {
    __hip_atomic_store(p, v, __ATOMIC_RELAXED, __HIP_MEMORY_SCOPE_AGENT);
}
__device__ __forceinline__ void agent_st16(u16* p, u16 v) {
    __hip_atomic_store(p, v, __ATOMIC_RELAXED, __HIP_MEMORY_SCOPE_AGENT);
}

// Relaxed-only grid barrier: NO acquire/release (no buffer_inv/buffer_wbl2).
// Sound because all cross-block data uses sc1 (IF-coherent) accesses and
// the explicit vmcnt drain happens before thread 0 signals arrival.
__device__ __forceinline__ void grid_barrier(u32* bars, int id) {
    __syncthreads();
    if (threadIdx.x == 0) {
        u32* base = bars + id * 8 * BAR_STRIDE;
        asm volatile("s_waitcnt vmcnt(0) lgkmcnt(0)" ::: "memory");
        __hip_atomic_fetch_add(base + (blockIdx.x & 7) * BAR_STRIDE, 1u,
                               __ATOMIC_RELAXED, __HIP_MEMORY_SCOPE_AGENT);
        u32 sum;
        do {
            sum = 0;
#pragma unroll
            for (int g = 0; g < 8; ++g)
                sum += __hip_atomic_load(base + g * BAR_STRIDE,
                                         __ATOMIC_RELAXED, __HIP_MEMORY_SCOPE_AGENT);
            if (sum < (u32)NBLK) __builtin_amdgcn_s_sleep(4);
        } while (sum < (u32)NBLK);
        asm volatile("" ::: "memory");
    }
    __syncthreads();
}

__device__ __forceinline__ float fast_tanh_half(float x) {
    // tanh(x/2) = sign(x) * (1 - e^-|x|) / (1 + e^-|x|)
    float ax = fabsf(x);
    float e = __expf(-ax);
    return copysignf((1.0f - e) / (1.0f + e), x);
}

__global__ __launch_bounds__(NTHR, 4)   // cap VGPR at 128: keep 16 waves/CU
void bp_fused(const float* __restrict__ H,      // (C, V)
              const float* __restrict__ synd,   // (B, C)
              const float* __restrict__ llr,    // (B, V)
              const float* __restrict__ w_vc_p,
              const float* __restrict__ w_cv_p,
              const float* __restrict__ damp_p,
              int* __restrict__ row_cnt, int* __restrict__ col_cnt,
              u16* __restrict__ row_idx, u16* __restrict__ col_idx,
              float* __restrict__ bel, float* __restrict__ cms,
              u32* __restrict__ bars,
              float* __restrict__ out) {        // (B, V)
    const int tid = blockIdx.x * NTHR + threadIdx.x;
    const int lane = threadIdx.x & 63;

    __shared__ u32 lds_edges[(NTHR / 64) * WCAP];   // 16 KB: per-wave edge lists
    u32* const wl = lds_edges + (threadIdx.x >> 6) * WCAP;

    // ---- P0: zero CSR region + dummy pads (sc1 -> IF) + init state ----
    {
        u32* zp = (u32*)row_cnt;   // row_cnt..col_idx contiguous (host layout)
        for (int t = tid; t < ZERO_WORDS; t += NTH) agent_st32(&zp[t], 0u);
        // dummy gather targets: bel[V_NUM*B + 0..31], cms[C_NUM*B + 0..31]
        if (tid < 32) agent_stf(&bel[V_NUM * B_NUM + tid], 0.0f);
        else if (tid < 64) agent_stf(&cms[C_NUM * B_NUM + (tid - 32)], 0.0f);
    }
    float llr_r[2], bel_r[2];
#pragma unroll
    for (int r = 0; r < 2; ++r) {
        int i = tid + r * NTH;          // V_NUM*B_NUM == 2*NTH
        int b = i & 31, v = i >> 5;
        float x = llr[b * V_NUM + v];
        llr_r[r] = x; bel_r[r] = x;
        agent_stf(&bel[i], x);
    }
    float ss_r;
    {
        int b = tid & 31, c = tid >> 5;  // C_NUM*B_NUM == NTH
        ss_r = 1.0f - 2.0f * synd[b * C_NUM + c];
    }

    // ---- P1a: stream dense H, compact nonzeros into per-wave LDS list ----
    // Hand-pipelined: next iteration's loads are issued BEFORE the branchy
    // ballot compaction of the current one (the per-BB scheduler won't hoist
    // loads across 16 branches by itself), keeping 2 loads/wave in flight.
    int wave_cnt;
    {
        const float4* Hv = (const float4*)H;
        const u64 ltmask = (1ull << lane) - 1ull;
        int wb = 0;                      // running per-wave edge count (uniform)
        int t = tid;
        float4 c0 = Hv[t];
        float4 c1 = Hv[t + NTH];
#pragma unroll 1
        for (int itn = 0; itn < 64; ++itn) {
            float4 n0, n1;
            int tn = t + 2 * NTH;
            if (itn < 63) { n0 = Hv[tn]; n1 = Hv[tn + NTH]; }
            float vals[8] = {c0.x, c0.y, c0.z, c0.w, c1.x, c1.y, c1.z, c1.w};
#pragma unroll
            for (int k = 0; k < 8; ++k) {
                bool nz = vals[k] != 0.0f;
                u64 b = __ballot(nz);
                if (b) {
                    if (nz) {
                        int ee = (k < 4) ? (t * 4 + k)
                                         : ((t + NTH) * 4 + (k - 4));
                        int off = wb + (int)__popcll(b & ltmask);
                        if (off < WCAP) wl[off] = (u32)ee;  // plain LDS store
                    }
                    wb += (int)__popcll(b);
                }
            }
            c0 = n0; c1 = n1; t = tn;
        }
        wave_cnt = wb < WCAP ? wb : WCAP;
    }
    // Barrier: all blocks finished zeroing counters/pads AND bel inits visible.
    grid_barrier(bars, 0);

    // ---- P1b: CSR insertion from LDS edge lists (~33 edges/wave) ----
    {
        for (int e = lane; e < wave_cnt; e += 64) {
            u32 ee = wl[e];
            int c = (int)(ee >> 14);             // V = 2^14
            int v = (int)(ee & (V_NUM - 1));
            int rs = atomicAdd(&row_cnt[c], 1);  // device-scope -> IF
            if (rs < RW) agent_st16(&row_idx[c * RW + rs], (u16)v);
            int cs = atomicAdd(&col_cnt[v], 1);
            if (cs < CW) agent_st16(&col_idx[v * CW + cs], (u16)c);
        }
    }
    grid_barrier(bars, 1);

    // ---- preload CSR indices into registers (loop-invariant across P2) ----
    // Tail slots are replaced by DUMMY indices (V_NUM / C_NUM) that gather a
    // zeroed pad line, so phases need no per-element masking. All accesses
    // are fully unrolled -> arrays stay in VGPRs (56 total for idx).
    int nrow_r;
    u64 rq[RQ];
    {
        int n = agent_ldi(&row_cnt[tid >> 5]);
        nrow_r = n > 4 * RQ ? 4 * RQ : n;
        const u64* q4 = (const u64*)(row_idx + (tid >> 5) * RW);
#pragma unroll
        for (int p = 0; p < RQ; ++p) {
            u64 q = agent_ld64(&q4[p]);
            int j = 4 * p;
            u64 a0 = (j + 0 < nrow_r) ? (q & 0xFFFFu) : (u64)V_NUM;
            u64 a1 = (j + 1 < nrow_r) ? ((q >> 16) & 0xFFFFu) : (u64)V_NUM;
            u64 a2 = (j + 2 < nrow_r) ? ((q >> 32) & 0xFFFFu) : (u64)V_NUM;
            u64 a3 = (j + 3 < nrow_r) ? (q >> 48) : (u64)V_NUM;
            rq[p] = a0 | (a1 << 16) | (a2 << 32) | (a3 << 48);
        }
    }
    int ncol_r[2];
    u64 cq[2][CQ];
#pragma unroll
    for (int r = 0; r < 2; ++r) {
        int v = (tid + r * NTH) >> 5;
        int n = agent_ldi(&col_cnt[v]);
        ncol_r[r] = n > 4 * CQ ? 4 * CQ : n;
        const u64* q4 = (const u64*)(col_idx + v * CW);
#pragma unroll
        for (int p = 0; p < CQ; ++p) {
            u64 q = agent_ld64(&q4[p]);
            int j = 4 * p;
            u64 a0 = (j + 0 < ncol_r[r]) ? (q & 0xFFFFu) : (u64)C_NUM;
            u64 a1 = (j + 1 < ncol_r[r]) ? ((q >> 16) & 0xFFFFu) : (u64)C_NUM;
            u64 a2 = (j + 2 < ncol_r[r]) ? ((q >> 32) & 0xFFFFu) : (u64)C_NUM;
            u64 a3 = (j + 3 < ncol_r[r]) ? (q >> 48) : (u64)C_NUM;
            cq[r][p] = a0 | (a1 << 16) | (a2 << 32) | (a3 << 48);
        }
    }
    const float wvc = w_vc_p[0];
    const float wcv = w_cv_p[0];
    const float d   = damp_p[0];

    // ---- P2: 15 BP iterations (gathers straight from register indices) ----
    const int b_lo = tid & 31;
    int barid = 2;
    for (int it = 0; it < 15; ++it) {
        // v->c : cms[c,b] = ss * tanh(0.5*wvc * sum bel[row]); 1 item/thread
        {
            float sum = 0.0f;
#pragma unroll
            for (int p = 0; p < RQ; ++p) {
                if (4 * p < nrow_r) {
                    u64 q = rq[p];
                    int i0 = (int)(q & 0xFFFFu);
                    int i1 = (int)((q >> 16) & 0xFFFFu);
                    int i2 = (int)((q >> 32) & 0xFFFFu);
                    int i3 = (int)(q >> 48);
                    float s0 = agent_ldf(&bel[i0 * B_NUM + b_lo]);
                    float s1 = agent_ldf(&bel[i1 * B_NUM + b_lo]);
                    float s2 = agent_ldf(&bel[i2 * B_NUM + b_lo]);
                    float s3 = agent_ldf(&bel[i3 * B_NUM + b_lo]);
                    sum += s0; sum += s1; sum += s2; sum += s3;
                }
            }
            agent_stf(&cms[tid], ss_r * fast_tanh_half(wvc * sum));
        }
        grid_barrier(bars, barid++);

        // c->v : bel = d*bel + (1-d)*(llr + wcv*sum cms[col]); 2 items/thread
        bool last = (it == 14);
#pragma unroll
        for (int r = 0; r < 2; ++r) {
            float sum = 0.0f;
#pragma unroll
            for (int p = 0; p < CQ; ++p) {
                if (4 * p < ncol_r[r]) {
                    u64 q = cq[r][p];
                    int i0 = (int)(q & 0xFFFFu);
                    int i1 = (int)((q >> 16) & 0xFFFFu);
                    int i2 = (int)((q >> 32) & 0xFFFFu);
                    int i3 = (int)(q >> 48);
                    float s0 = agent_ldf(&cms[i0 * B_NUM + b_lo]);
                    float s1 = agent_ldf(&cms[i1 * B_NUM + b_lo]);
                    float s2 = agent_ldf(&cms[i2 * B_NUM + b_lo]);
                    float s3 = agent_ldf(&cms[i3 * B_NUM + b_lo]);
                    sum += s0; sum += s1; sum += s2; sum += s3;
                }
            }
            float nb = d * bel_r[r] + (1.0f - d) * (llr_r[r] + wcv * sum);
            bel_r[r] = nb;
            int i = tid + r * NTH;
            if (!last) {
                agent_stf(&bel[i], nb);
            } else {
                // fused epilogue; kernel-end release makes it visible
                int b = i & 31, v = i >> 5;
                out[b * V_NUM + v] = 1.0f / (1.0f + __expf(nb));
            }
        }
        if (!last) grid_barrier(bars, barid++);
    }
}

extern "C" void kernel_launch(void* const* d_in, const int* in_sizes, int n_in,
                              void* d_out, int out_size, void* d_ws, size_t ws_size,
                              hipStream_t stream) {
    const float* synd = (const float*)d_in[0];   // (B, C)
    const float* H    = (const float*)d_in[1];   // (C, V)
    const float* llr  = (const float*)d_in[2];   // (B, V)
    const float* w_vc = (const float*)d_in[3];
    const float* w_cv = (const float*)d_in[4];
    const float* damp = (const float*)d_in[5];
    float* out = (float*)d_out;

    // ws layout: CSR region CONTIGUOUS (kernel zero-fills it as one span);
    // bel/cms each get a 128B zeroed dummy pad (+256B alloc for alignment).
    char* ws = (char*)d_ws;
    size_t off = 0;
    int* row_cnt = (int*)(ws + off); off += (size_t)C_NUM * 4;        // 32 KB
    int* col_cnt = (int*)(ws + off); off += (size_t)V_NUM * 4;        // 64 KB
    u16* row_idx = (u16*)(ws + off); off += (size_t)C_NUM * RW * 2;   // 1 MB
    u16* col_idx = (u16*)(ws + off); off += (size_t)V_NUM * CW * 2;   // 1 MB
    float* bel = (float*)(ws + off); off += (size_t)V_NUM * B_NUM * 4 + 256; // 2 MB + pad
    float* cms = (float*)(ws + off); off += (size_t)C_NUM * B_NUM * 4 + 256; // 1 MB + pad
    u32* bars  = (u32*)(ws + off); off += (size_t)NBAR * 8 * BAR_STRIDE * 4; // 63.5 KB

    // Only the barrier counters need host-side zeroing (ws arrives 0xAA)
    hipMemsetAsync(bars, 0, (size_t)NBAR * 8 * BAR_STRIDE * 4, stream);

    void* args[] = {
        (void*)&H, (void*)&synd, (void*)&llr,
        (void*)&w_vc, (void*)&w_cv, (void*)&damp,
        (void*)&row_cnt, (void*)&col_cnt, (void*)&row_idx, (void*)&col_idx,
        (void*)&bel, (void*)&cms, (void*)&bars, (void*)&out
    };
    hipLaunchCooperativeKernel((const void*)bp_fused,
                               dim3(NBLK), dim3(NTHR), args, 0, stream);
}

// Round 3
// 1149.254 us; speedup vs baseline: 1.0087x; 1.0087x over previous
//
#include <hip/hip_runtime.h>

// NeuralBPDecoder: sparse BP over a 0.1%-dense parity matrix.
// Round 9: round 8's register-resident CSR indices, with the register
// budget FIXED. Round-8 post-mortem: __launch_bounds__(NTHR, 4) capped
// VGPRs at 64 (8 waves/SIMD occupancy request), so the preloaded index
// arrays (56 VGPRs) spilled to scratch -> +590 MB of HBM traffic
// (FETCH 398->857 MB) re-loading them every iteration, VALUBusy 9->3.7%,
// 425 -> 599 us. The grid is 1 block/CU (256x1024 on 256 CUs) = 4
// waves/SIMD by construction, which allows 128 VGPR/wave at FULL
// occupancy. launch_bounds(NTHR, 1) restores that cap; everything else
// is identical to round 8 (clean A/B on register budget).

#define C_NUM 8192
#define V_NUM 16384
#define B_NUM 32
#define RW 64   // storage slots per check row (mean nnz 16.4)
#define CW 32   // storage slots per var col  (mean nnz  8.2)

#define RQ 12   // register u64 batches per row: 48 idx (max row nnz ~33)
#define CQ 8    // register u64 batches per col: 32 idx (max col nnz ~20)

#define NBLK 256
#define NTHR 1024
#define NTH (NBLK * NTHR)   // 262144 threads, 16 waves/CU

#define WCAP 256            // LDS edge slots per wave (mean 32.8, >30 sigma safe)

typedef unsigned short u16;
typedef unsigned int u32;
typedef unsigned long long u64;

#define ZERO_WORDS ((C_NUM * 4 + V_NUM * 4 + C_NUM * RW * 2 + V_NUM * CW * 2) / 4)
#define NBAR 31
#define BAR_STRIDE 64              // u32s between counters (256 B)

__device__ __forceinline__ float agent_ldf(const float* p) {
    return __hip_atomic_load(p, __ATOMIC_RELAXED, __HIP_MEMORY_SCOPE_AGENT);
}
__device__ __forceinline__ void agent_stf(float* p, float v) {
    __hip_atomic_store(p, v, __ATOMIC_RELAXED, __HIP_MEMORY_SCOPE_AGENT);
}
__device__ __forceinline__ u64 agent_ld64(const u64* p) {
    return __hip_atomic_load(p, __ATOMIC_RELAXED, __HIP_MEMORY_SCOPE_AGENT);
}
__device__ __forceinline__ int agent_ldi(const int* p) {
    return __hip_atomic_load(p, __ATOMIC_RELAXED, __HIP_MEMORY_SCOPE_AGENT);
}
__device__ __forceinline__ void agent_st32(u32* p, u32 v) {
    __hip_atomic_store(p, v, __ATOMIC_RELAXED, __HIP_MEMORY_SCOPE_AGENT);
}
__device__ __forceinline__ void agent_st16(u16* p, u16 v) {
    __hip_atomic_store(p, v, __ATOMIC_RELAXED, __HIP_MEMORY_SCOPE_AGENT);
}

// Relaxed-only grid barrier: NO acquire/release (no buffer_inv/buffer_wbl2).
// Sound because all cross-block data uses sc1 (IF-coherent) accesses and
// the explicit vmcnt drain happens before thread 0 signals arrival.
__device__ __forceinline__ void grid_barrier(u32* bars, int id) {
    __syncthreads();
    if (threadIdx.x == 0) {
        u32* base = bars + id * 8 * BAR_STRIDE;
        asm volatile("s_waitcnt vmcnt(0) lgkmcnt(0)" ::: "memory");
        __hip_atomic_fetch_add(base + (blockIdx.x & 7) * BAR_STRIDE, 1u,
                               __ATOMIC_RELAXED, __HIP_MEMORY_SCOPE_AGENT);
        u32 sum;
        do {
            sum = 0;
#pragma unroll
            for (int g = 0; g < 8; ++g)
                sum += __hip_atomic_load(base + g * BAR_STRIDE,
                                         __ATOMIC_RELAXED, __HIP_MEMORY_SCOPE_AGENT);
            if (sum < (u32)NBLK) __builtin_amdgcn_s_sleep(4);
        } while (sum < (u32)NBLK);
        asm volatile("" ::: "memory");
    }
    __syncthreads();
}

__device__ __forceinline__ float fast_tanh_half(float x) {
    // tanh(x/2) = sign(x) * (1 - e^-|x|) / (1 + e^-|x|)
    float ax = fabsf(x);
    float e = __expf(-ax);
    return copysignf((1.0f - e) / (1.0f + e), x);
}

__global__ __launch_bounds__(NTHR, 1)   // 1 block/CU: full 128-VGPR budget
void bp_fused(const float* __restrict__ H,      // (C, V)
              const float* __restrict__ synd,   // (B, C)
              const float* __restrict__ llr,    // (B, V)
              const float* __restrict__ w_vc_p,
              const float* __restrict__ w_cv_p,
              const float* __restrict__ damp_p,
              int* __restrict__ row_cnt, int* __restrict__ col_cnt,
              u16* __restrict__ row_idx, u16* __restrict__ col_idx,
              float* __restrict__ bel, float* __restrict__ cms,
              u32* __restrict__ bars,
              float* __restrict__ out) {        // (B, V)
    const int tid = blockIdx.x * NTHR + threadIdx.x;
    const int lane = threadIdx.x & 63;

    __shared__ u32 lds_edges[(NTHR / 64) * WCAP];   // 16 KB: per-wave edge lists
    u32* const wl = lds_edges + (threadIdx.x >> 6) * WCAP;

    // ---- P0: zero CSR region + dummy pads (sc1 -> IF) + init state ----
    {
        u32* zp = (u32*)row_cnt;   // row_cnt..col_idx contiguous (host layout)
        for (int t = tid; t < ZERO_WORDS; t += NTH) agent_st32(&zp[t], 0u);
        // dummy gather targets: bel[V_NUM*B + 0..31], cms[C_NUM*B + 0..31]
        if (tid < 32) agent_stf(&bel[V_NUM * B_NUM + tid], 0.0f);
        else if (tid < 64) agent_stf(&cms[C_NUM * B_NUM + (tid - 32)], 0.0f);
    }
    float llr_r[2], bel_r[2];
#pragma unroll
    for (int r = 0; r < 2; ++r) {
        int i = tid + r * NTH;          // V_NUM*B_NUM == 2*NTH
        int b = i & 31, v = i >> 5;
        float x = llr[b * V_NUM + v];
        llr_r[r] = x; bel_r[r] = x;
        agent_stf(&bel[i], x);
    }
    float ss_r;
    {
        int b = tid & 31, c = tid >> 5;  // C_NUM*B_NUM == NTH
        ss_r = 1.0f - 2.0f * synd[b * C_NUM + c];
    }

    // ---- P1a: stream dense H, compact nonzeros into per-wave LDS list ----
    // Hand-pipelined: next iteration's loads are issued BEFORE the branchy
    // ballot compaction of the current one (the per-BB scheduler won't hoist
    // loads across 16 branches by itself), keeping 2 loads/wave in flight.
    int wave_cnt;
    {
        const float4* Hv = (const float4*)H;
        const u64 ltmask = (1ull << lane) - 1ull;
        int wb = 0;                      // running per-wave edge count (uniform)
        int t = tid;
        float4 c0 = Hv[t];
        float4 c1 = Hv[t + NTH];
#pragma unroll 1
        for (int itn = 0; itn < 64; ++itn) {
            float4 n0, n1;
            int tn = t + 2 * NTH;
            if (itn < 63) { n0 = Hv[tn]; n1 = Hv[tn + NTH]; }
            float vals[8] = {c0.x, c0.y, c0.z, c0.w, c1.x, c1.y, c1.z, c1.w};
#pragma unroll
            for (int k = 0; k < 8; ++k) {
                bool nz = vals[k] != 0.0f;
                u64 b = __ballot(nz);
                if (b) {
                    if (nz) {
                        int ee = (k < 4) ? (t * 4 + k)
                                         : ((t + NTH) * 4 + (k - 4));
                        int off = wb + (int)__popcll(b & ltmask);
                        if (off < WCAP) wl[off] = (u32)ee;  // plain LDS store
                    }
                    wb += (int)__popcll(b);
                }
            }
            c0 = n0; c1 = n1; t = tn;
        }
        wave_cnt = wb < WCAP ? wb : WCAP;
    }
    // Barrier: all blocks finished zeroing counters/pads AND bel inits visible.
    grid_barrier(bars, 0);

    // ---- P1b: CSR insertion from LDS edge lists (~33 edges/wave) ----
    {
        for (int e = lane; e < wave_cnt; e += 64) {
            u32 ee = wl[e];
            int c = (int)(ee >> 14);             // V = 2^14
            int v = (int)(ee & (V_NUM - 1));
            int rs = atomicAdd(&row_cnt[c], 1);  // device-scope -> IF
            if (rs < RW) agent_st16(&row_idx[c * RW + rs], (u16)v);
            int cs = atomicAdd(&col_cnt[v], 1);
            if (cs < CW) agent_st16(&col_idx[v * CW + cs], (u16)c);
        }
    }
    grid_barrier(bars, 1);

    // ---- preload CSR indices into registers (loop-invariant across P2) ----
    // Tail slots are replaced by DUMMY indices (V_NUM / C_NUM) that gather a
    // zeroed pad line, so phases need no per-element masking. All accesses
    // are fully unrolled -> arrays stay in VGPRs (56 total for idx).
    int nrow_r;
    u64 rq[RQ];
    {
        int n = agent_ldi(&row_cnt[tid >> 5]);
        nrow_r = n > 4 * RQ ? 4 * RQ : n;
        const u64* q4 = (const u64*)(row_idx + (tid >> 5) * RW);
#pragma unroll
        for (int p = 0; p < RQ; ++p) {
            u64 q = agent_ld64(&q4[p]);
            int j = 4 * p;
            u64 a0 = (j + 0 < nrow_r) ? (q & 0xFFFFu) : (u64)V_NUM;
            u64 a1 = (j + 1 < nrow_r) ? ((q >> 16) & 0xFFFFu) : (u64)V_NUM;
            u64 a2 = (j + 2 < nrow_r) ? ((q >> 32) & 0xFFFFu) : (u64)V_NUM;
            u64 a3 = (j + 3 < nrow_r) ? (q >> 48) : (u64)V_NUM;
            rq[p] = a0 | (a1 << 16) | (a2 << 32) | (a3 << 48);
        }
    }
    int ncol_r[2];
    u64 cq[2][CQ];
#pragma unroll
    for (int r = 0; r < 2; ++r) {
        int v = (tid + r * NTH) >> 5;
        int n = agent_ldi(&col_cnt[v]);
        ncol_r[r] = n > 4 * CQ ? 4 * CQ : n;
        const u64* q4 = (const u64*)(col_idx + v * CW);
#pragma unroll
        for (int p = 0; p < CQ; ++p) {
            u64 q = agent_ld64(&q4[p]);
            int j = 4 * p;
            u64 a0 = (j + 0 < ncol_r[r]) ? (q & 0xFFFFu) : (u64)C_NUM;
            u64 a1 = (j + 1 < ncol_r[r]) ? ((q >> 16) & 0xFFFFu) : (u64)C_NUM;
            u64 a2 = (j + 2 < ncol_r[r]) ? ((q >> 32) & 0xFFFFu) : (u64)C_NUM;
            u64 a3 = (j + 3 < ncol_r[r]) ? (q >> 48) : (u64)C_NUM;
            cq[r][p] = a0 | (a1 << 16) | (a2 << 32) | (a3 << 48);
        }
    }
    const float wvc = w_vc_p[0];
    const float wcv = w_cv_p[0];
    const float d   = damp_p[0];

    // ---- P2: 15 BP iterations (gathers straight from register indices) ----
    const int b_lo = tid & 31;
    int barid = 2;
    for (int it = 0; it < 15; ++it) {
        // v->c : cms[c,b] = ss * tanh(0.5*wvc * sum bel[row]); 1 item/thread
        {
            float sum = 0.0f;
#pragma unroll
            for (int p = 0; p < RQ; ++p) {
                if (4 * p < nrow_r) {
                    u64 q = rq[p];
                    int i0 = (int)(q & 0xFFFFu);
                    int i1 = (int)((q >> 16) & 0xFFFFu);
                    int i2 = (int)((q >> 32) & 0xFFFFu);
                    int i3 = (int)(q >> 48);
                    float s0 = agent_ldf(&bel[i0 * B_NUM + b_lo]);
                    float s1 = agent_ldf(&bel[i1 * B_NUM + b_lo]);
                    float s2 = agent_ldf(&bel[i2 * B_NUM + b_lo]);
                    float s3 = agent_ldf(&bel[i3 * B_NUM + b_lo]);
                    sum += s0; sum += s1; sum += s2; sum += s3;
                }
            }
            agent_stf(&cms[tid], ss_r * fast_tanh_half(wvc * sum));
        }
        grid_barrier(bars, barid++);

        // c->v : bel = d*bel + (1-d)*(llr + wcv*sum cms[col]); 2 items/thread
        bool last = (it == 14);
#pragma unroll
        for (int r = 0; r < 2; ++r) {
            float sum = 0.0f;
#pragma unroll
            for (int p = 0; p < CQ; ++p) {
                if (4 * p < ncol_r[r]) {
                    u64 q = cq[r][p];
                    int i0 = (int)(q & 0xFFFFu);
                    int i1 = (int)((q >> 16) & 0xFFFFu);
                    int i2 = (int)((q >> 32) & 0xFFFFu);
                    int i3 = (int)(q >> 48);
                    float s0 = agent_ldf(&cms[i0 * B_NUM + b_lo]);
                    float s1 = agent_ldf(&cms[i1 * B_NUM + b_lo]);
                    float s2 = agent_ldf(&cms[i2 * B_NUM + b_lo]);
                    float s3 = agent_ldf(&cms[i3 * B_NUM + b_lo]);
                    sum += s0; sum += s1; sum += s2; sum += s3;
                }
            }
            float nb = d * bel_r[r] + (1.0f - d) * (llr_r[r] + wcv * sum);
            bel_r[r] = nb;
            int i = tid + r * NTH;
            if (!last) {
                agent_stf(&bel[i], nb);
            } else {
                // fused epilogue; kernel-end release makes it visible
                int b = i & 31, v = i >> 5;
                out[b * V_NUM + v] = 1.0f / (1.0f + __expf(nb));
            }
        }
        if (!last) grid_barrier(bars, barid++);
    }
}

extern "C" void kernel_launch(void* const* d_in, const int* in_sizes, int n_in,
                              void* d_out, int out_size, void* d_ws, size_t ws_size,
                              hipStream_t stream) {
    const float* synd = (const float*)d_in[0];   // (B, C)
    const float* H    = (const float*)d_in[1];   // (C, V)
    const float* llr  = (const float*)d_in[2];   // (B, V)
    const float* w_vc = (const float*)d_in[3];
    const float* w_cv = (const float*)d_in[4];
    const float* damp = (const float*)d_in[5];
    float* out = (float*)d_out;

    // ws layout: CSR region CONTIGUOUS (kernel zero-fills it as one span);
    // bel/cms each get a 128B zeroed dummy pad (+256B alloc for alignment).
    char* ws = (char*)d_ws;
    size_t off = 0;
    int* row_cnt = (int*)(ws + off); off += (size_t)C_NUM * 4;        // 32 KB
    int* col_cnt = (int*)(ws + off); off += (size_t)V_NUM * 4;        // 64 KB
    u16* row_idx = (u16*)(ws + off); off += (size_t)C_NUM * RW * 2;   // 1 MB
    u16* col_idx = (u16*)(ws + off); off += (size_t)V_NUM * CW * 2;   // 1 MB
    float* bel = (float*)(ws + off); off += (size_t)V_NUM * B_NUM * 4 + 256; // 2 MB + pad
    float* cms = (float*)(ws + off); off += (size_t)C_NUM * B_NUM * 4 + 256; // 1 MB + pad
    u32* bars  = (u32*)(ws + off); off += (size_t)NBAR * 8 * BAR_STRIDE * 4; // 63.5 KB

    // Only the barrier counters need host-side zeroing (ws arrives 0xAA)
    hipMemsetAsync(bars, 0, (size_t)NBAR * 8 * BAR_STRIDE * 4, stream);

    void* args[] = {
        (void*)&H, (void*)&synd, (void*)&llr,
        (void*)&w_vc, (void*)&w_cv, (void*)&damp,
        (void*)&row_cnt, (void*)&col_cnt, (void*)&row_idx, (void*)&col_idx,
        (void*)&bel, (void*)&cms, (void*)&bars, (void*)&out
    };
    hipLaunchCooperativeKernel((const void*)bp_fused,
                               dim3(NBLK), dim3(NTHR), args, 0, stream);
}

// Round 4
// 927.299 us; speedup vs baseline: 1.2501x; 1.2394x over previous
//
#include <hip/hip_runtime.h>

// NeuralBPDecoder: sparse BP over a 0.1%-dense parity matrix.
// Round 10: CSR indices moved to LDS (shared per row/col group), replacing
// rounds 8/9's register-resident attempt. Post-mortem of r8/r9: hipcc's
// allocator targeted the 64-VGPR (8 waves/EU) boundary regardless of
// __launch_bounds__, spilling the 56-VGPR index arrays to scratch ->
// +460MB FETCH / +129MB WRITE re-reading them every iteration (857MB
// FETCH, 600us). Key realization: indices are SHARED by the 32 threads of
// a b-group (all use row c = tid>>5), so per block they are only
// 32 rows x 48 + 64 cols x 32 u16 = 7KB -> LDS. P2 phases read them with
// ds_read_b64 (32-lane broadcast, 2 addrs/wave = free), then issue all
// gathers back-to-back: phase critical path = LDS ~120cy + ONE IF round
// trip, with ~40 VGPRs and no spill risk. Everything else (relaxed-only
// IF-coherent barrier, ballot-compaction scan, fused epilogue) unchanged.

#define C_NUM 8192
#define V_NUM 16384
#define B_NUM 32
#define RW 64   // storage slots per check row (mean nnz 16.4)
#define CW 32   // storage slots per var col  (mean nnz  8.2)

#define RQ 12   // u64 batches per row kept in LDS: 48 idx (max row nnz ~33)
#define CQ 8    // u64 batches per col kept in LDS: 32 idx (max col nnz ~20)

#define NBLK 256
#define NTHR 1024
#define NTH (NBLK * NTHR)   // 262144 threads, 16 waves/CU

#define WCAP 256            // LDS edge slots per wave (mean 32.8, >30 sigma safe)

typedef unsigned short u16;
typedef unsigned int u32;
typedef unsigned long long u64;

#define ZERO_WORDS ((C_NUM * 4 + V_NUM * 4 + C_NUM * RW * 2 + V_NUM * CW * 2) / 4)
#define NBAR 31
#define BAR_STRIDE 64              // u32s between counters (256 B)

__device__ __forceinline__ float agent_ldf(const float* p) {
    return __hip_atomic_load(p, __ATOMIC_RELAXED, __HIP_MEMORY_SCOPE_AGENT);
}
__device__ __forceinline__ void agent_stf(float* p, float v) {
    __hip_atomic_store(p, v, __ATOMIC_RELAXED, __HIP_MEMORY_SCOPE_AGENT);
}
__device__ __forceinline__ u64 agent_ld64(const u64* p) {
    return __hip_atomic_load(p, __ATOMIC_RELAXED, __HIP_MEMORY_SCOPE_AGENT);
}
__device__ __forceinline__ int agent_ldi(const int* p) {
    return __hip_atomic_load(p, __ATOMIC_RELAXED, __HIP_MEMORY_SCOPE_AGENT);
}
__device__ __forceinline__ void agent_st32(u32* p, u32 v) {
    __hip_atomic_store(p, v, __ATOMIC_RELAXED, __HIP_MEMORY_SCOPE_AGENT);
}
__device__ __forceinline__ void agent_st16(u16* p, u16 v) {
    __hip_atomic_store(p, v, __ATOMIC_RELAXED, __HIP_MEMORY_SCOPE_AGENT);
}

// Relaxed-only grid barrier: NO acquire/release (no buffer_inv/buffer_wbl2).
// Sound because all cross-block data uses sc1 (IF-coherent) accesses and
// the explicit vmcnt drain happens before thread 0 signals arrival.
__device__ __forceinline__ void grid_barrier(u32* bars, int id) {
    __syncthreads();
    if (threadIdx.x == 0) {
        u32* base = bars + id * 8 * BAR_STRIDE;
        asm volatile("s_waitcnt vmcnt(0) lgkmcnt(0)" ::: "memory");
        __hip_atomic_fetch_add(base + (blockIdx.x & 7) * BAR_STRIDE, 1u,
                               __ATOMIC_RELAXED, __HIP_MEMORY_SCOPE_AGENT);
        u32 sum;
        do {
            sum = 0;
#pragma unroll
            for (int g = 0; g < 8; ++g)
                sum += __hip_atomic_load(base + g * BAR_STRIDE,
                                         __ATOMIC_RELAXED, __HIP_MEMORY_SCOPE_AGENT);
            if (sum < (u32)NBLK) __builtin_amdgcn_s_sleep(4);
        } while (sum < (u32)NBLK);
        asm volatile("" ::: "memory");
    }
    __syncthreads();
}

__device__ __forceinline__ float fast_tanh_half(float x) {
    // tanh(x/2) = sign(x) * (1 - e^-|x|) / (1 + e^-|x|)
    float ax = fabsf(x);
    float e = __expf(-ax);
    return copysignf((1.0f - e) / (1.0f + e), x);
}

__global__ __launch_bounds__(NTHR, 1)
void bp_fused(const float* __restrict__ H,      // (C, V)
              const float* __restrict__ synd,   // (B, C)
              const float* __restrict__ llr,    // (B, V)
              const float* __restrict__ w_vc_p,
              const float* __restrict__ w_cv_p,
              const float* __restrict__ damp_p,
              int* __restrict__ row_cnt, int* __restrict__ col_cnt,
              u16* __restrict__ row_idx, u16* __restrict__ col_idx,
              float* __restrict__ bel, float* __restrict__ cms,
              u32* __restrict__ bars,
              float* __restrict__ out) {        // (B, V)
    const int tid = blockIdx.x * NTHR + threadIdx.x;
    const int lane = threadIdx.x & 63;

    __shared__ u32 lds_edges[(NTHR / 64) * WCAP];   // 16 KB: per-wave edge lists
    __shared__ u64 ls_row64[32 * RQ];               //  3 KB: this block's row idx
    __shared__ u64 ls_col64[64 * CQ];               //  4 KB: this block's col idx
    u32* const wl = lds_edges + (threadIdx.x >> 6) * WCAP;

    // ---- P0: zero CSR region + dummy pads (sc1 -> IF) + init state ----
    {
        u32* zp = (u32*)row_cnt;   // row_cnt..col_idx contiguous (host layout)
        for (int t = tid; t < ZERO_WORDS; t += NTH) agent_st32(&zp[t], 0u);
        // dummy gather targets: bel[V_NUM*B + 0..31], cms[C_NUM*B + 0..31]
        if (tid < 32) agent_stf(&bel[V_NUM * B_NUM + tid], 0.0f);
        else if (tid < 64) agent_stf(&cms[C_NUM * B_NUM + (tid - 32)], 0.0f);
    }
    float llr_r[2], bel_r[2];
#pragma unroll
    for (int r = 0; r < 2; ++r) {
        int i = tid + r * NTH;          // V_NUM*B_NUM == 2*NTH
        int b = i & 31, v = i >> 5;
        float x = llr[b * V_NUM + v];
        llr_r[r] = x; bel_r[r] = x;
        agent_stf(&bel[i], x);
    }
    float ss_r;
    {
        int b = tid & 31, c = tid >> 5;  // C_NUM*B_NUM == NTH
        ss_r = 1.0f - 2.0f * synd[b * C_NUM + c];
    }

    // ---- P1a: stream dense H, compact nonzeros into per-wave LDS list ----
    // Hand-pipelined: next iteration's loads are issued BEFORE the branchy
    // ballot compaction of the current one, keeping 2 loads/wave in flight.
    int wave_cnt;
    {
        const float4* Hv = (const float4*)H;
        const u64 ltmask = (1ull << lane) - 1ull;
        int wb = 0;                      // running per-wave edge count (uniform)
        int t = tid;
        float4 c0 = Hv[t];
        float4 c1 = Hv[t + NTH];
#pragma unroll 1
        for (int itn = 0; itn < 64; ++itn) {
            float4 n0, n1;
            int tn = t + 2 * NTH;
            if (itn < 63) { n0 = Hv[tn]; n1 = Hv[tn + NTH]; }
            float vals[8] = {c0.x, c0.y, c0.z, c0.w, c1.x, c1.y, c1.z, c1.w};
#pragma unroll
            for (int k = 0; k < 8; ++k) {
                bool nz = vals[k] != 0.0f;
                u64 b = __ballot(nz);
                if (b) {
                    if (nz) {
                        int ee = (k < 4) ? (t * 4 + k)
                                         : ((t + NTH) * 4 + (k - 4));
                        int off = wb + (int)__popcll(b & ltmask);
                        if (off < WCAP) wl[off] = (u32)ee;  // plain LDS store
                    }
                    wb += (int)__popcll(b);
                }
            }
            c0 = n0; c1 = n1; t = tn;
        }
        wave_cnt = wb < WCAP ? wb : WCAP;
    }
    // Barrier: all blocks finished zeroing counters/pads AND bel inits visible.
    grid_barrier(bars, 0);

    // ---- P1b: CSR insertion from LDS edge lists (~33 edges/wave) ----
    {
        for (int e = lane; e < wave_cnt; e += 64) {
            u32 ee = wl[e];
            int c = (int)(ee >> 14);             // V = 2^14
            int v = (int)(ee & (V_NUM - 1));
            int rs = atomicAdd(&row_cnt[c], 1);  // device-scope -> IF
            if (rs < RW) agent_st16(&row_idx[c * RW + rs], (u16)v);
            int cs = atomicAdd(&col_cnt[v], 1);
            if (cs < CW) agent_st16(&col_idx[v * CW + cs], (u16)c);
        }
    }
    grid_barrier(bars, 1);

    // ---- copy this block's CSR indices into LDS (shared per group) ----
    // Rows owned: c = blockIdx*32 + g, g in [0,32)   -> 32*RQ = 384 u64
    // Cols owned: v = blockIdx*32 + g (r=0) and 8192 + blockIdx*32 + g (r=1)
    //                                              -> 64*CQ = 512 u64
    // Tail slots replaced by DUMMY idx (V_NUM / C_NUM) -> zeroed pad line,
    // so P2 phases need no per-element masking.
    {
        int t = threadIdx.x;
        if (t < 32 * RQ) {                        // threads 0..383: row idx
            int g = t / RQ, p = t - g * RQ;
            int c = (blockIdx.x << 5) + g;
            int n = agent_ldi(&row_cnt[c]);
            n = n > 4 * RQ ? 4 * RQ : n;
            u64 q = agent_ld64(&((const u64*)(row_idx + c * RW))[p]);
            int j = 4 * p;
            u64 a0 = (j + 0 < n) ? (q & 0xFFFFu) : (u64)V_NUM;
            u64 a1 = (j + 1 < n) ? ((q >> 16) & 0xFFFFu) : (u64)V_NUM;
            u64 a2 = (j + 2 < n) ? ((q >> 32) & 0xFFFFu) : (u64)V_NUM;
            u64 a3 = (j + 3 < n) ? (q >> 48) : (u64)V_NUM;
            ls_row64[t] = a0 | (a1 << 16) | (a2 << 32) | (a3 << 48);
        } else if (t >= 512) {                    // threads 512..1023: col idx
            int t2 = t - 512;
            int g = t2 >> 3, p = t2 & 7;
            int v = (g < 32) ? ((blockIdx.x << 5) + g)
                             : (C_NUM + (blockIdx.x << 5) + (g - 32));
            int n = agent_ldi(&col_cnt[v]);
            n = n > 4 * CQ ? 4 * CQ : n;
            u64 q = agent_ld64(&((const u64*)(col_idx + v * CW))[p]);
            int j = 4 * p;
            u64 a0 = (j + 0 < n) ? (q & 0xFFFFu) : (u64)C_NUM;
            u64 a1 = (j + 1 < n) ? ((q >> 16) & 0xFFFFu) : (u64)C_NUM;
            u64 a2 = (j + 2 < n) ? ((q >> 32) & 0xFFFFu) : (u64)C_NUM;
            u64 a3 = (j + 3 < n) ? (q >> 48) : (u64)C_NUM;
            ls_col64[t2] = a0 | (a1 << 16) | (a2 << 32) | (a3 << 48);
        }
    }
    // per-thread batch-skip counts (uniform within each 32-thread group)
    int nrow_r;
    {
        int n = agent_ldi(&row_cnt[tid >> 5]);
        nrow_r = n > 4 * RQ ? 4 * RQ : n;
    }
    int ncol_r[2];
#pragma unroll
    for (int r = 0; r < 2; ++r) {
        int n = agent_ldi(&col_cnt[(tid + r * NTH) >> 5]);
        ncol_r[r] = n > 4 * CQ ? 4 * CQ : n;
    }
    const float wvc = w_vc_p[0];
    const float wcv = w_cv_p[0];
    const float d   = damp_p[0];
    __syncthreads();     // LDS idx visible block-wide

    // ---- P2: 15 BP iterations (idx from LDS broadcast, single IF round) ----
    const int b_lo = tid & 31;
    const u64* const rowL  = ls_row64 + (threadIdx.x >> 5) * RQ;
    const u64* const colL0 = ls_col64 + (threadIdx.x >> 5) * CQ;
    const u64* const colL1 = ls_col64 + (32 + (threadIdx.x >> 5)) * CQ;
    int barid = 2;
    for (int it = 0; it < 15; ++it) {
        // v->c : cms[c,b] = ss * tanh(0.5*wvc * sum bel[row]); 1 item/thread
        {
            float sum = 0.0f;
#pragma unroll
            for (int p = 0; p < RQ; ++p) {
                if (4 * p < nrow_r) {
                    u64 q = rowL[p];             // ds_read_b64, 32-lane bcast
                    int i0 = (int)(q & 0xFFFFu);
                    int i1 = (int)((q >> 16) & 0xFFFFu);
                    int i2 = (int)((q >> 32) & 0xFFFFu);
                    int i3 = (int)(q >> 48);
                    float s0 = agent_ldf(&bel[i0 * B_NUM + b_lo]);
                    float s1 = agent_ldf(&bel[i1 * B_NUM + b_lo]);
                    float s2 = agent_ldf(&bel[i2 * B_NUM + b_lo]);
                    float s3 = agent_ldf(&bel[i3 * B_NUM + b_lo]);
                    sum += s0; sum += s1; sum += s2; sum += s3;
                }
            }
            agent_stf(&cms[tid], ss_r * fast_tanh_half(wvc * sum));
        }
        grid_barrier(bars, barid++);

        // c->v : bel = d*bel + (1-d)*(llr + wcv*sum cms[col]); 2 items/thread
        bool last = (it == 14);
#pragma unroll
        for (int r = 0; r < 2; ++r) {
            const u64* colL = r ? colL1 : colL0;
            float sum = 0.0f;
#pragma unroll
            for (int p = 0; p < CQ; ++p) {
                if (4 * p < ncol_r[r]) {
                    u64 q = colL[p];
                    int i0 = (int)(q & 0xFFFFu);
                    int i1 = (int)((q >> 16) & 0xFFFFu);
                    int i2 = (int)((q >> 32) & 0xFFFFu);
                    int i3 = (int)(q >> 48);
                    float s0 = agent_ldf(&cms[i0 * B_NUM + b_lo]);
                    float s1 = agent_ldf(&cms[i1 * B_NUM + b_lo]);
                    float s2 = agent_ldf(&cms[i2 * B_NUM + b_lo]);
                    float s3 = agent_ldf(&cms[i3 * B_NUM + b_lo]);
                    sum += s0; sum += s1; sum += s2; sum += s3;
                }
            }
            float nb = d * bel_r[r] + (1.0f - d) * (llr_r[r] + wcv * sum);
            bel_r[r] = nb;
            int i = tid + r * NTH;
            if (!last) {
                agent_stf(&bel[i], nb);
            } else {
                // fused epilogue; kernel-end release makes it visible
                int b = i & 31, v = i >> 5;
                out[b * V_NUM + v] = 1.0f / (1.0f + __expf(nb));
            }
        }
        if (!last) grid_barrier(bars, barid++);
    }
}

extern "C" void kernel_launch(void* const* d_in, const int* in_sizes, int n_in,
                              void* d_out, int out_size, void* d_ws, size_t ws_size,
                              hipStream_t stream) {
    const float* synd = (const float*)d_in[0];   // (B, C)
    const float* H    = (const float*)d_in[1];   // (C, V)
    const float* llr  = (const float*)d_in[2];   // (B, V)
    const float* w_vc = (const float*)d_in[3];
    const float* w_cv = (const float*)d_in[4];
    const float* damp = (const float*)d_in[5];
    float* out = (float*)d_out;

    // ws layout: CSR region CONTIGUOUS (kernel zero-fills it as one span);
    // bel/cms each get a 128B zeroed dummy pad (+256B alloc for alignment).
    char* ws = (char*)d_ws;
    size_t off = 0;
    int* row_cnt = (int*)(ws + off); off += (size_t)C_NUM * 4;        // 32 KB
    int* col_cnt = (int*)(ws + off); off += (size_t)V_NUM * 4;        // 64 KB
    u16* row_idx = (u16*)(ws + off); off += (size_t)C_NUM * RW * 2;   // 1 MB
    u16* col_idx = (u16*)(ws + off); off += (size_t)V_NUM * CW * 2;   // 1 MB
    float* bel = (float*)(ws + off); off += (size_t)V_NUM * B_NUM * 4 + 256; // 2 MB + pad
    float* cms = (float*)(ws + off); off += (size_t)C_NUM * B_NUM * 4 + 256; // 1 MB + pad
    u32* bars  = (u32*)(ws + off); off += (size_t)NBAR * 8 * BAR_STRIDE * 4; // 63.5 KB

    // Only the barrier counters need host-side zeroing (ws arrives 0xAA)
    hipMemsetAsync(bars, 0, (size_t)NBAR * 8 * BAR_STRIDE * 4, stream);

    void* args[] = {
        (void*)&H, (void*)&synd, (void*)&llr,
        (void*)&w_vc, (void*)&w_cv, (void*)&damp,
        (void*)&row_cnt, (void*)&col_cnt, (void*)&row_idx, (void*)&col_idx,
        (void*)&bel, (void*)&cms, (void*)&bars, (void*)&out
    };
    hipLaunchCooperativeKernel((const void*)bp_fused,
                               dim3(NBLK), dim3(NTHR), args, 0, stream);
}

// Round 5
// 925.521 us; speedup vs baseline: 1.2525x; 1.0019x over previous
//
#include <hip/hip_runtime.h>

// NeuralBPDecoder: sparse BP over a 0.1%-dense parity matrix.
// Round 11: mid-iteration grid barrier replaced by TAGGED-DATAFLOW sync on
// cms. Round-10 budget: scan ~85us (HBM floor), P0/P1b ~25us, P2 gathers
// ~1-2us/phase -> the remaining ~200us is 29 barrier crossings x (arrival +
// poll-detect + MAX per-block skew) ~ 4-6us each. A global barrier charges
// everyone for the slowest block 29x. Now each cms value is a tagged u64
// (hi32 = it+1, lo32 = float bits), double-buffered by parity; c->v spins
// only on the ~8-16 values it actually consumes. End-of-iteration barrier
// kept: it bounds parity-slot reuse (producer of it+2 must pass barriers
// it and it+1 first), so "tag >= want" == ready, exactly. Stale tags from
// the previous dispatch are invalidated by zeroing cms in P0. Dummy slots:
// once-written tag 0xFFFFFFFF pads (always ready, value 0). Barriers
// 31 -> 16. Scan prefetch deepened to 2 iterations ahead (4 loads in
// flight). Relaxed-only IF-coherent barrier impl unchanged.

#define C_NUM 8192
#define V_NUM 16384
#define B_NUM 32
#define RW 64   // storage slots per check row (mean nnz 16.4)
#define CW 32   // storage slots per var col  (mean nnz  8.2)

#define RQ 12   // u64 idx batches per row in LDS: 48 idx (max row nnz ~33)
#define CQ 8    // u64 idx batches per col in LDS: 32 idx (max col nnz ~20)

#define NBLK 256
#define NTHR 1024
#define NTH (NBLK * NTHR)   // 262144 threads, 16 waves/CU

#define WCAP 256            // LDS edge slots per wave (mean 32.8, >30 sigma safe)

typedef unsigned short u16;
typedef unsigned int u32;
typedef unsigned long long u64;

#define CSTRIDE (C_NUM * B_NUM + 32)   // u64s per cms parity buffer (+32 pad)
// zero span A: row_cnt..col_idx + cms parity-0 main region
#define ZW_A ((C_NUM * 4 + V_NUM * 4 + C_NUM * RW * 2 + V_NUM * CW * 2 + C_NUM * B_NUM * 8) / 4)
// zero span B: cms parity-1 main region
#define ZW_B (C_NUM * B_NUM * 8 / 4)
#define NBAR 31
#define BAR_STRIDE 64              // u32s between counters (256 B)

__device__ __forceinline__ float agent_ldf(const float* p) {
    return __hip_atomic_load(p, __ATOMIC_RELAXED, __HIP_MEMORY_SCOPE_AGENT);
}
__device__ __forceinline__ void agent_stf(float* p, float v) {
    __hip_atomic_store(p, v, __ATOMIC_RELAXED, __HIP_MEMORY_SCOPE_AGENT);
}
__device__ __forceinline__ u64 agent_ld64(const u64* p) {
    return __hip_atomic_load(p, __ATOMIC_RELAXED, __HIP_MEMORY_SCOPE_AGENT);
}
__device__ __forceinline__ void agent_st64(u64* p, u64 v) {
    __hip_atomic_store(p, v, __ATOMIC_RELAXED, __HIP_MEMORY_SCOPE_AGENT);
}
__device__ __forceinline__ int agent_ldi(const int* p) {
    return __hip_atomic_load(p, __ATOMIC_RELAXED, __HIP_MEMORY_SCOPE_AGENT);
}
__device__ __forceinline__ void agent_st32(u32* p, u32 v) {
    __hip_atomic_store(p, v, __ATOMIC_RELAXED, __HIP_MEMORY_SCOPE_AGENT);
}
__device__ __forceinline__ void agent_st16(u16* p, u16 v) {
    __hip_atomic_store(p, v, __ATOMIC_RELAXED, __HIP_MEMORY_SCOPE_AGENT);
}

// Relaxed-only grid barrier: NO acquire/release (no buffer_inv/buffer_wbl2).
// Sound because all cross-block data uses sc1 (IF-coherent) accesses and
// the explicit vmcnt drain happens before thread 0 signals arrival.
__device__ __forceinline__ void grid_barrier(u32* bars, int id) {
    __syncthreads();
    if (threadIdx.x == 0) {
        u32* base = bars + id * 8 * BAR_STRIDE;
        asm volatile("s_waitcnt vmcnt(0) lgkmcnt(0)" ::: "memory");
        __hip_atomic_fetch_add(base + (blockIdx.x & 7) * BAR_STRIDE, 1u,
                               __ATOMIC_RELAXED, __HIP_MEMORY_SCOPE_AGENT);
        u32 sum;
        do {
            sum = 0;
#pragma unroll
            for (int g = 0; g < 8; ++g)
                sum += __hip_atomic_load(base + g * BAR_STRIDE,
                                         __ATOMIC_RELAXED, __HIP_MEMORY_SCOPE_AGENT);
            if (sum < (u32)NBLK) __builtin_amdgcn_s_sleep(4);
        } while (sum < (u32)NBLK);
        asm volatile("" ::: "memory");
    }
    __syncthreads();
}

__device__ __forceinline__ float fast_tanh_half(float x) {
    // tanh(x/2) = sign(x) * (1 - e^-|x|) / (1 + e^-|x|)
    float ax = fabsf(x);
    float e = __expf(-ax);
    return copysignf((1.0f - e) / (1.0f + e), x);
}

__global__ __launch_bounds__(NTHR, 1)
void bp_fused(const float* __restrict__ H,      // (C, V)
              const float* __restrict__ synd,   // (B, C)
              const float* __restrict__ llr,    // (B, V)
              const float* __restrict__ w_vc_p,
              const float* __restrict__ w_cv_p,
              const float* __restrict__ damp_p,
              int* __restrict__ row_cnt, int* __restrict__ col_cnt,
              u16* __restrict__ row_idx, u16* __restrict__ col_idx,
              u64* __restrict__ cmst,           // [2][CSTRIDE] tagged cms
              float* __restrict__ bel,
              u32* __restrict__ bars,
              float* __restrict__ out) {        // (B, V)
    const int tid = blockIdx.x * NTHR + threadIdx.x;
    const int lane = threadIdx.x & 63;

    __shared__ u32 lds_edges[(NTHR / 64) * WCAP];   // 16 KB: per-wave edge lists
    __shared__ u64 ls_row64[32 * RQ];               //  3 KB: this block's row idx
    __shared__ u64 ls_col64[64 * CQ];               //  4 KB: this block's col idx
    u32* const wl = lds_edges + (threadIdx.x >> 6) * WCAP;

    // ---- P0: zero CSR + cms regions (tag invalidation!) + pads + state ----
    {
        u32* zp = (u32*)row_cnt;   // row_cnt..col_idx..cms0 contiguous
        for (int t = tid; t < ZW_A; t += NTH) agent_st32(&zp[t], 0u);
        u32* zq = (u32*)(cmst + CSTRIDE);           // cms parity-1 main
        for (int t = tid; t < ZW_B; t += NTH) agent_st32(&zq[t], 0u);
        // dummy pads: bel pad = 0.0f; cms pads = tag 0xFFFFFFFF (always
        // ready), value bits 0 -> contributes 0.0f to sums.
        if (tid < 32) agent_stf(&bel[V_NUM * B_NUM + tid], 0.0f);
        else if (tid < 64)
            agent_st64(&cmst[C_NUM * B_NUM + (tid - 32)], 0xFFFFFFFF00000000ull);
        else if (tid < 96)
            agent_st64(&cmst[CSTRIDE + C_NUM * B_NUM + (tid - 64)], 0xFFFFFFFF00000000ull);
    }
    float llr_r[2], bel_r[2];
#pragma unroll
    for (int r = 0; r < 2; ++r) {
        int i = tid + r * NTH;          // V_NUM*B_NUM == 2*NTH
        int b = i & 31, v = i >> 5;
        float x = llr[b * V_NUM + v];
        llr_r[r] = x; bel_r[r] = x;
        agent_stf(&bel[i], x);
    }
    float ss_r;
    {
        int b = tid & 31, c = tid >> 5;  // C_NUM*B_NUM == NTH
        ss_r = 1.0f - 2.0f * synd[b * C_NUM + c];
    }

    // ---- P1a: stream dense H, compact nonzeros into per-wave LDS list ----
    // Depth-2 hand pipeline: loads for iterations itn+1 AND itn+2 are in
    // flight while itn is processed (4 outstanding float4 loads/wave).
    int wave_cnt;
    {
        const float4* Hv = (const float4*)H;
        const u64 ltmask = (1ull << lane) - 1ull;
        int wb = 0;                      // running per-wave edge count (uniform)
        int ta = tid;
        int tb = tid + 2 * NTH;
        float4 a0 = Hv[ta], a1 = Hv[ta + NTH];
        float4 b0 = Hv[tb], b1 = Hv[tb + NTH];
#pragma unroll 1
        for (int itn = 0; itn < 64; ++itn) {
            int tc = tb + 2 * NTH;
            float4 p0, p1;
            if (itn < 62) { p0 = Hv[tc]; p1 = Hv[tc + NTH]; }
            float vals[8] = {a0.x, a0.y, a0.z, a0.w, a1.x, a1.y, a1.z, a1.w};
#pragma unroll
            for (int k = 0; k < 8; ++k) {
                bool nz = vals[k] != 0.0f;
                u64 b = __ballot(nz);
                if (b) {
                    if (nz) {
                        int ee = (k < 4) ? (ta * 4 + k)
                                         : ((ta + NTH) * 4 + (k - 4));
                        int off = wb + (int)__popcll(b & ltmask);
                        if (off < WCAP) wl[off] = (u32)ee;  // plain LDS store
                    }
                    wb += (int)__popcll(b);
                }
            }
            a0 = b0; a1 = b1; b0 = p0; b1 = p1; ta = tb; tb = tc;
        }
        wave_cnt = wb < WCAP ? wb : WCAP;
    }
    // Barrier: all blocks finished zeroing counters/cms/pads AND bel inits.
    grid_barrier(bars, 0);

    // ---- P1b: CSR insertion from LDS edge lists (~33 edges/wave) ----
    {
        for (int e = lane; e < wave_cnt; e += 64) {
            u32 ee = wl[e];
            int c = (int)(ee >> 14);             // V = 2^14
            int v = (int)(ee & (V_NUM - 1));
            int rs = atomicAdd(&row_cnt[c], 1);  // device-scope -> IF
            if (rs < RW) agent_st16(&row_idx[c * RW + rs], (u16)v);
            int cs = atomicAdd(&col_cnt[v], 1);
            if (cs < CW) agent_st16(&col_idx[v * CW + cs], (u16)c);
        }
    }
    grid_barrier(bars, 1);

    // ---- copy this block's CSR indices into LDS (shared per group) ----
    // Tail slots replaced by DUMMY idx (V_NUM / C_NUM) -> pad entries,
    // so P2 phases need no per-element masking.
    {
        int t = threadIdx.x;
        if (t < 32 * RQ) {                        // threads 0..383: row idx
            int g = t / RQ, p = t - g * RQ;
            int c = (blockIdx.x << 5) + g;
            int n = agent_ldi(&row_cnt[c]);
            n = n > 4 * RQ ? 4 * RQ : n;
            u64 q = agent_ld64(&((const u64*)(row_idx + c * RW))[p]);
            int j = 4 * p;
            u64 a0 = (j + 0 < n) ? (q & 0xFFFFu) : (u64)V_NUM;
            u64 a1 = (j + 1 < n) ? ((q >> 16) & 0xFFFFu) : (u64)V_NUM;
            u64 a2 = (j + 2 < n) ? ((q >> 32) & 0xFFFFu) : (u64)V_NUM;
            u64 a3 = (j + 3 < n) ? (q >> 48) : (u64)V_NUM;
            ls_row64[t] = a0 | (a1 << 16) | (a2 << 32) | (a3 << 48);
        } else if (t >= 512) {                    // threads 512..1023: col idx
            int t2 = t - 512;
            int g = t2 >> 3, p = t2 & 7;
            int v = (g < 32) ? ((blockIdx.x << 5) + g)
                             : (C_NUM + (blockIdx.x << 5) + (g - 32));
            int n = agent_ldi(&col_cnt[v]);
            n = n > 4 * CQ ? 4 * CQ : n;
            u64 q = agent_ld64(&((const u64*)(col_idx + v * CW))[p]);
            int j = 4 * p;
            u64 a0 = (j + 0 < n) ? (q & 0xFFFFu) : (u64)C_NUM;
            u64 a1 = (j + 1 < n) ? ((q >> 16) & 0xFFFFu) : (u64)C_NUM;
            u64 a2 = (j + 2 < n) ? ((q >> 32) & 0xFFFFu) : (u64)C_NUM;
            u64 a3 = (j + 3 < n) ? (q >> 48) : (u64)C_NUM;
            ls_col64[t2] = a0 | (a1 << 16) | (a2 << 32) | (a3 << 48);
        }
    }
    // per-thread batch-skip counts (uniform within each 32-thread group)
    int nrow_r;
    {
        int n = agent_ldi(&row_cnt[tid >> 5]);
        nrow_r = n > 4 * RQ ? 4 * RQ : n;
    }
    int ncol_r[2];
#pragma unroll
    for (int r = 0; r < 2; ++r) {
        int n = agent_ldi(&col_cnt[(tid + r * NTH) >> 5]);
        ncol_r[r] = n > 4 * CQ ? 4 * CQ : n;
    }
    const float wvc = w_vc_p[0];
    const float wcv = w_cv_p[0];
    const float d   = damp_p[0];
    __syncthreads();     // LDS idx visible block-wide

    // ---- P2: 15 BP iterations; ONE barrier per iteration. v->c publishes
    // tagged cms; c->v spins only on the values it consumes. ----
    const int b_lo = tid & 31;
    const u64* const rowL  = ls_row64 + (threadIdx.x >> 5) * RQ;
    const u64* const colL0 = ls_col64 + (threadIdx.x >> 5) * CQ;
    const u64* const colL1 = ls_col64 + (32 + (threadIdx.x >> 5)) * CQ;
    int barid = 2;
    for (int it = 0; it < 15; ++it) {
        const u32 want = (u32)(it + 1);
        u64* const cw = cmst + (size_t)(it & 1) * CSTRIDE;
        // v->c : cms[c,b] = tag(it+1) | ss * tanh(0.5*wvc * sum bel[row])
        {
            float sum = 0.0f;
#pragma unroll
            for (int p = 0; p < RQ; ++p) {
                if (4 * p < nrow_r) {
                    u64 q = rowL[p];             // ds_read_b64, 32-lane bcast
                    int i0 = (int)(q & 0xFFFFu);
                    int i1 = (int)((q >> 16) & 0xFFFFu);
                    int i2 = (int)((q >> 32) & 0xFFFFu);
                    int i3 = (int)(q >> 48);
                    float s0 = agent_ldf(&bel[i0 * B_NUM + b_lo]);
                    float s1 = agent_ldf(&bel[i1 * B_NUM + b_lo]);
                    float s2 = agent_ldf(&bel[i2 * B_NUM + b_lo]);
                    float s3 = agent_ldf(&bel[i3 * B_NUM + b_lo]);
                    sum += s0; sum += s1; sum += s2; sum += s3;
                }
            }
            float m = ss_r * fast_tanh_half(wvc * sum);
            agent_st64(&cw[tid], ((u64)want << 32) | (u64)__float_as_uint(m));
        }
        // NO mid-iteration barrier: consumers spin on tags below.

        // c->v : bel = d*bel + (1-d)*(llr + wcv*sum cms[col]); 2 items/thread
        bool last = (it == 14);
#pragma unroll
        for (int r = 0; r < 2; ++r) {
            const u64* colL = r ? colL1 : colL0;
            float sum = 0.0f;
#pragma unroll
            for (int p = 0; p < CQ; ++p) {
                if (4 * p < ncol_r[r]) {
                    u64 q = colL[p];
                    int i0 = (int)(q & 0xFFFFu);
                    int i1 = (int)((q >> 16) & 0xFFFFu);
                    int i2 = (int)((q >> 32) & 0xFFFFu);
                    int i3 = (int)(q >> 48);
                    u64* a0 = &cw[(size_t)i0 * B_NUM + b_lo];
                    u64* a1 = &cw[(size_t)i1 * B_NUM + b_lo];
                    u64* a2 = &cw[(size_t)i2 * B_NUM + b_lo];
                    u64* a3 = &cw[(size_t)i3 * B_NUM + b_lo];
                    u64 g0 = agent_ld64(a0);
                    u64 g1 = agent_ld64(a1);
                    u64 g2 = agent_ld64(a2);
                    u64 g3 = agent_ld64(a3);
                    // spin only on stale values (tag monotone: >=want == ready)
                    for (;;) {
                        bool bad0 = (u32)(g0 >> 32) < want;
                        bool bad1 = (u32)(g1 >> 32) < want;
                        bool bad2 = (u32)(g2 >> 32) < want;
                        bool bad3 = (u32)(g3 >> 32) < want;
                        if (!(bad0 | bad1 | bad2 | bad3)) break;
                        __builtin_amdgcn_s_sleep(1);
                        if (bad0) g0 = agent_ld64(a0);
                        if (bad1) g1 = agent_ld64(a1);
                        if (bad2) g2 = agent_ld64(a2);
                        if (bad3) g3 = agent_ld64(a3);
                    }
                    sum += __uint_as_float((u32)g0);
                    sum += __uint_as_float((u32)g1);
                    sum += __uint_as_float((u32)g2);
                    sum += __uint_as_float((u32)g3);
                }
            }
            float nb = d * bel_r[r] + (1.0f - d) * (llr_r[r] + wcv * sum);
            bel_r[r] = nb;
            int i = tid + r * NTH;
            if (!last) {
                agent_stf(&bel[i], nb);
            } else {
                // fused epilogue; kernel-end release makes it visible
                int b = i & 31, v = i >> 5;
                out[b * V_NUM + v] = 1.0f / (1.0f + __expf(nb));
            }
        }
        // End-of-iteration barrier: publishes bel for it+1's v->c AND bounds
        // cms parity-slot reuse (producer of it+2 must pass 2 barriers).
        if (!last) grid_barrier(bars, barid++);
    }
}

extern "C" void kernel_launch(void* const* d_in, const int* in_sizes, int n_in,
                              void* d_out, int out_size, void* d_ws, size_t ws_size,
                              hipStream_t stream) {
    const float* synd = (const float*)d_in[0];   // (B, C)
    const float* H    = (const float*)d_in[1];   // (C, V)
    const float* llr  = (const float*)d_in[2];   // (B, V)
    const float* w_vc = (const float*)d_in[3];
    const float* w_cv = (const float*)d_in[4];
    const float* damp = (const float*)d_in[5];
    float* out = (float*)d_out;

    // ws layout: CSR region + cms parity-0 CONTIGUOUS (zero span A);
    // cms parity-1 = zero span B; pads excluded from zero spans.
    char* ws = (char*)d_ws;
    size_t off = 0;
    int* row_cnt = (int*)(ws + off); off += (size_t)C_NUM * 4;        // 32 KB
    int* col_cnt = (int*)(ws + off); off += (size_t)V_NUM * 4;        // 64 KB
    u16* row_idx = (u16*)(ws + off); off += (size_t)C_NUM * RW * 2;   // 1 MB
    u16* col_idx = (u16*)(ws + off); off += (size_t)V_NUM * CW * 2;   // 1 MB
    u64* cmst = (u64*)(ws + off); off += (size_t)2 * CSTRIDE * 8;     // 4 MB tagged cms
    float* bel = (float*)(ws + off); off += (size_t)(V_NUM * B_NUM + 64) * 4; // 2 MB + pad
    u32* bars  = (u32*)(ws + off); off += (size_t)NBAR * 8 * BAR_STRIDE * 4;  // 63.5 KB

    // Only the barrier counters need host-side zeroing (ws arrives 0xAA)
    hipMemsetAsync(bars, 0, (size_t)NBAR * 8 * BAR_STRIDE * 4, stream);

    void* args[] = {
        (void*)&H, (void*)&synd, (void*)&llr,
        (void*)&w_vc, (void*)&w_cv, (void*)&damp,
        (void*)&row_cnt, (void*)&col_cnt, (void*)&row_idx, (void*)&col_idx,
        (void*)&cmst, (void*)&bel, (void*)&bars, (void*)&out
    };
    hipLaunchCooperativeKernel((const void*)bp_fused,
                               dim3(NBLK), dim3(NTHR), args, 0, stream);
}

// Round 6
// 921.518 us; speedup vs baseline: 1.2579x; 1.0043x over previous
//
#include <hip/hip_runtime.h>

// NeuralBPDecoder: sparse BP over a 0.1%-dense parity matrix.
// Round 12: XCD-LOCAL P2. Post-mortem r11: barriers cost 0.4us each (14
// removed bought 6us) -> P2's ~230us is the GATHER TRAFFIC: agent (sc1)
// accesses bypass the per-XCD L2s, so every iteration pulls ~50MB through
// Infinity Fabric at ~2TB/s effective. Fix: the 32 batches are independent;
// slice them 4-per-XCD so each XCD's bel slice (256KB) + cms slice (128KB)
// are resident in ITS 4MB L2. Blocks read HW_REG_XCC_ID (HW-verified) and
// self-assign ranks; LDS padded to 82KB forces 1 block/CU -> exactly 32
// blocks/XCD, CHECKED at runtime; else a fallback path (virtual groups +
// agent accesses == round-10 behavior) keeps correctness independent of
// placement. Intra-XCD coherence: plain stores (write-through to L2, vmcnt
// drained by __syncthreads before each barrier) + sc0 gathers (SE scope:
// L1-bypass, L2-served per gfx94x SC[1:0] = {00 CU, 01 SE, 10 dev, 11 sys}).
// cms tags dropped (4B messages, 2 barriers/iter). Scan/CSR build unchanged.

#define C_NUM 8192
#define V_NUM 16384
#define B_NUM 32
#define RW 64   // storage slots per check row (mean nnz 16.4)
#define CW 32   // storage slots per var col  (mean nnz  8.2)

#define RQ 12   // u64 idx batches per row in LDS: 48 idx (max row nnz ~33)
#define CQ 8    // u64 idx batches per col in LDS: 32 idx (max col nnz ~20)
#define RQ_S 13 // LDS row stride (u64) - breaks bank alignment
#define CQ_S 9  // LDS col stride (u64)

#define NBLK 256
#define NTHR 1024
#define NTH (NBLK * NTHR)   // 262144 threads, 16 waves/CU

#define WCAP 256            // LDS edge slots per wave (mean 32.8, >30 sigma safe)

#define BEL_SL (16400 * 4)  // floats per bel slice (dummy vi=16384 pad inside)
#define CMS_SL (8200 * 4)   // floats per cms slice (dummy ci=8192 pad inside)

typedef unsigned short u16;
typedef unsigned int u32;
typedef unsigned long long u64;

#define ZERO_WORDS ((C_NUM + V_NUM))        // row_cnt+col_cnt ints only
#define NBAR 32
#define BAR_STRIDE 64              // u32s between counters (256 B)

__device__ __forceinline__ float agent_ldf(const float* p) {
    return __hip_atomic_load(p, __ATOMIC_RELAXED, __HIP_MEMORY_SCOPE_AGENT);
}
__device__ __forceinline__ void agent_stf(float* p, float v) {
    __hip_atomic_store(p, v, __ATOMIC_RELAXED, __HIP_MEMORY_SCOPE_AGENT);
}
__device__ __forceinline__ u64 agent_ld64(const u64* p) {
    return __hip_atomic_load(p, __ATOMIC_RELAXED, __HIP_MEMORY_SCOPE_AGENT);
}
__device__ __forceinline__ int agent_ldi(const int* p) {
    return __hip_atomic_load(p, __ATOMIC_RELAXED, __HIP_MEMORY_SCOPE_AGENT);
}
__device__ __forceinline__ void agent_st32(u32* p, u32 v) {
    __hip_atomic_store(p, v, __ATOMIC_RELAXED, __HIP_MEMORY_SCOPE_AGENT);
}
__device__ __forceinline__ void agent_st16(u16* p, u16 v) {
    __hip_atomic_store(p, v, __ATOMIC_RELAXED, __HIP_MEMORY_SCOPE_AGENT);
}

// Relaxed-only grid barrier. Sound because: __syncthreads drains vmcnt in
// every thread (stores committed to their coherence point) before thread 0
// signals; cross-XCD data uses sc1 (IF); intra-XCD data only needs L2.
__device__ __forceinline__ void grid_barrier(u32* bars, int id) {
    __syncthreads();
    if (threadIdx.x == 0) {
        u32* base = bars + id * 8 * BAR_STRIDE;
        asm volatile("s_waitcnt vmcnt(0) lgkmcnt(0)" ::: "memory");
        __hip_atomic_fetch_add(base + (blockIdx.x & 7) * BAR_STRIDE, 1u,
                               __ATOMIC_RELAXED, __HIP_MEMORY_SCOPE_AGENT);
        u32 sum;
        do {
            sum = 0;
#pragma unroll
            for (int g = 0; g < 8; ++g)
                sum += __hip_atomic_load(base + g * BAR_STRIDE,
                                         __ATOMIC_RELAXED, __HIP_MEMORY_SCOPE_AGENT);
            if (sum < (u32)NBLK) __builtin_amdgcn_s_sleep(4);
        } while (sum < (u32)NBLK);
        asm volatile("" ::: "memory");
    }
    __syncthreads();
}

__device__ __forceinline__ float fast_tanh_half(float x) {
    float ax = fabsf(x);
    float e = __expf(-ax);
    return copysignf((1.0f - e) / (1.0f + e), x);
}

// 4-wide gather. LOCAL: sc0 = SE scope (bypass CU L1, served by XCD L2).
// FALLBACK: agent (sc1 -> IF). Results flow through asm outputs, so the
// data dependence is explicit (no hoist hazard).
template<bool LOCAL>
__device__ __forceinline__ void ld4(const float* p0, const float* p1,
                                    const float* p2, const float* p3,
                                    float& r0, float& r1, float& r2, float& r3) {
    if (LOCAL) {
        asm volatile(
            "global_load_dword %0, %4, off sc0\n\t"
            "global_load_dword %1, %5, off sc0\n\t"
            "global_load_dword %2, %6, off sc0\n\t"
            "global_load_dword %3, %7, off sc0\n\t"
            "s_waitcnt vmcnt(0)"
            : "=&v"(r0), "=&v"(r1), "=&v"(r2), "=&v"(r3)
            : "v"(p0), "v"(p1), "v"(p2), "v"(p3)
            : "memory");
    } else {
        r0 = agent_ldf(p0); r1 = agent_ldf(p1);
        r2 = agent_ldf(p2); r3 = agent_ldf(p3);
    }
}

template<bool LOCAL>
__device__ __forceinline__ void decode_tail(
    int G, int R,
    const float* __restrict__ synd, const float* __restrict__ llr,
    const int* __restrict__ row_cnt, const int* __restrict__ col_cnt,
    const u16* __restrict__ row_idx, const u16* __restrict__ col_idx,
    float* __restrict__ bel_x, float* __restrict__ cms_x,
    u32* __restrict__ bars, float* __restrict__ out,
    u64* ls_row, u64* ls_col,
    float wvc, float wcv, float d)
{
    const int t = threadIdx.x;
    const int b4 = t & 3;
    const int qid = t >> 2;                  // 0..255
    float* const belS = bel_x + (size_t)G * BEL_SL;
    float* const cmsS = cms_x + (size_t)G * CMS_SL;

    // ---- copy this group's CSR indices into LDS (tails -> dummy idx) ----
    for (int e = t; e < 256 * RQ; e += NTHR) {
        int rl = e / RQ, p = e - rl * RQ;
        int c = (R << 8) + rl;
        int n = agent_ldi(&row_cnt[c]); n = n > 4 * RQ ? 4 * RQ : n;
        u64 q = agent_ld64(&((const u64*)(row_idx + (size_t)c * RW))[p]);
        int j = 4 * p;
        u64 a0 = (j + 0 < n) ? (q & 0xFFFFu) : (u64)V_NUM;
        u64 a1 = (j + 1 < n) ? ((q >> 16) & 0xFFFFu) : (u64)V_NUM;
        u64 a2 = (j + 2 < n) ? ((q >> 32) & 0xFFFFu) : (u64)V_NUM;
        u64 a3 = (j + 3 < n) ? (q >> 48) : (u64)V_NUM;
        ls_row[rl * RQ_S + p] = a0 | (a1 << 16) | (a2 << 32) | (a3 << 48);
    }
    for (int e = t; e < 512 * CQ; e += NTHR) {
        int gl = e >> 3, p = e & 7;
        int v = (gl < 256) ? ((R << 8) + gl) : (C_NUM + (R << 8) + (gl - 256));
        int n = agent_ldi(&col_cnt[v]); n = n > 4 * CQ ? 4 * CQ : n;
        u64 q = agent_ld64(&((const u64*)(col_idx + (size_t)v * CW))[p]);
        int j = 4 * p;
        u64 a0 = (j + 0 < n) ? (q & 0xFFFFu) : (u64)C_NUM;
        u64 a1 = (j + 1 < n) ? ((q >> 16) & 0xFFFFu) : (u64)C_NUM;
        u64 a2 = (j + 2 < n) ? ((q >> 32) & 0xFFFFu) : (u64)C_NUM;
        u64 a3 = (j + 3 < n) ? (q >> 48) : (u64)C_NUM;
        ls_col[gl * CQ_S + p] = a0 | (a1 << 16) | (a2 << 32) | (a3 << 48);
    }
    // ---- per-thread state ----
    const int c_my = (R << 8) + qid;
    const int v0_my = (R << 8) + qid;
    const int v1_my = C_NUM + (R << 8) + qid;
    int nrow;  { int n = agent_ldi(&row_cnt[c_my]);  nrow  = n > 4*RQ ? 4*RQ : n; }
    int ncol0; { int n = agent_ldi(&col_cnt[v0_my]); ncol0 = n > 4*CQ ? 4*CQ : n; }
    int ncol1; { int n = agent_ldi(&col_cnt[v1_my]); ncol1 = n > 4*CQ ? 4*CQ : n; }
    const int b = (G << 2) + b4;
    const float ss = 1.0f - 2.0f * synd[b * C_NUM + c_my];
    const float llr0 = llr[b * V_NUM + v0_my];
    const float llr1 = llr[b * V_NUM + v1_my];
    float bel0 = llr0, bel1 = llr1;
    if (LOCAL) {
        belS[v0_my * 4 + b4] = bel0;
        belS[v1_my * 4 + b4] = bel1;
    } else {
        agent_stf(&belS[v0_my * 4 + b4], bel0);
        agent_stf(&belS[v1_my * 4 + b4], bel1);
    }

    grid_barrier(bars, 2);   // bel init + LDS idx visible group-wide

    const u64* const rowL  = ls_row + qid * RQ_S;
    const u64* const colL0 = ls_col + qid * CQ_S;
    const u64* const colL1 = ls_col + (256 + qid) * CQ_S;
    float* const cms_own  = cmsS + c_my * 4 + b4;
    float* const bel_own0 = belS + v0_my * 4 + b4;
    float* const bel_own1 = belS + v1_my * 4 + b4;

    int barid = 3;
    for (int it = 0; it < 15; ++it) {
        // ---- v->c ----
        {
            float sum = 0.0f;
#pragma unroll
            for (int p = 0; p < RQ; ++p) {
                if (4 * p < nrow) {
                    u64 q = rowL[p];
                    const float* a0 = belS + (int)(q & 0xFFFFu) * 4 + b4;
                    const float* a1 = belS + (int)((q >> 16) & 0xFFFFu) * 4 + b4;
                    const float* a2 = belS + (int)((q >> 32) & 0xFFFFu) * 4 + b4;
                    const float* a3 = belS + (int)(q >> 48) * 4 + b4;
                    float s0, s1, s2, s3;
                    ld4<LOCAL>(a0, a1, a2, a3, s0, s1, s2, s3);
                    sum += s0; sum += s1; sum += s2; sum += s3;
                }
            }
            float m = ss * fast_tanh_half(wvc * sum);
            if (LOCAL) *cms_own = m; else agent_stf(cms_own, m);
        }
        grid_barrier(bars, barid++);

        // ---- c->v ----
        bool last = (it == 14);
        float sum0 = 0.0f, sum1 = 0.0f;
#pragma unroll
        for (int p = 0; p < CQ; ++p) {
            if (4 * p < ncol0) {
                u64 q = colL0[p];
                const float* a0 = cmsS + (int)(q & 0xFFFFu) * 4 + b4;
                const float* a1 = cmsS + (int)((q >> 16) & 0xFFFFu) * 4 + b4;
                const float* a2 = cmsS + (int)((q >> 32) & 0xFFFFu) * 4 + b4;
                const float* a3 = cmsS + (int)(q >> 48) * 4 + b4;
                float s0, s1, s2, s3;
                ld4<LOCAL>(a0, a1, a2, a3, s0, s1, s2, s3);
                sum0 += s0; sum0 += s1; sum0 += s2; sum0 += s3;
            }
        }
#pragma unroll
        for (int p = 0; p < CQ; ++p) {
            if (4 * p < ncol1) {
                u64 q = colL1[p];
                const float* a0 = cmsS + (int)(q & 0xFFFFu) * 4 + b4;
                const float* a1 = cmsS + (int)((q >> 16) & 0xFFFFu) * 4 + b4;
                const float* a2 = cmsS + (int)((q >> 32) & 0xFFFFu) * 4 + b4;
                const float* a3 = cmsS + (int)(q >> 48) * 4 + b4;
                float s0, s1, s2, s3;
                ld4<LOCAL>(a0, a1, a2, a3, s0, s1, s2, s3);
                sum1 += s0; sum1 += s1; sum1 += s2; sum1 += s3;
            }
        }
        float nb0 = d * bel0 + (1.0f - d) * (llr0 + wcv * sum0);
        float nb1 = d * bel1 + (1.0f - d) * (llr1 + wcv * sum1);
        bel0 = nb0; bel1 = nb1;
        if (!last) {
            if (LOCAL) { *bel_own0 = nb0; *bel_own1 = nb1; }
            else { agent_stf(bel_own0, nb0); agent_stf(bel_own1, nb1); }
            grid_barrier(bars, barid++);
        } else {
            out[b * V_NUM + v0_my] = 1.0f / (1.0f + __expf(nb0));
            out[b * V_NUM + v1_my] = 1.0f / (1.0f + __expf(nb1));
        }
    }
}

__global__ __launch_bounds__(NTHR, 1)
void bp_fused(const float* __restrict__ H,      // (C, V)
              const float* __restrict__ synd,   // (B, C)
              const float* __restrict__ llr,    // (B, V)
              const float* __restrict__ w_vc_p,
              const float* __restrict__ w_cv_p,
              const float* __restrict__ damp_p,
              int* __restrict__ row_cnt, int* __restrict__ col_cnt,
              u16* __restrict__ row_idx, u16* __restrict__ col_idx,
              float* __restrict__ bel_x, float* __restrict__ cms_x,
              u32* __restrict__ bars, int* __restrict__ xcd_cnt,
              float* __restrict__ out) {        // (B, V)
    const int tid = blockIdx.x * NTHR + threadIdx.x;
    const int lane = threadIdx.x & 63;

    // 82 KB static LDS: forces 1 block/CU (2 blocks would need 164 > 160),
    // so 256 blocks land 1-per-CU -> exactly 32 per XCD (checked anyway).
    __shared__ u32 lds_edges[(NTHR / 64) * WCAP + 1024];  // 20 KB (incl pad)
    __shared__ u64 ls_row[256 * RQ_S];                    // 26 KB
    __shared__ u64 ls_col[512 * CQ_S];                    // 36 KB
    __shared__ int s_xcd, s_rank;
    u32* const wl = lds_edges + (threadIdx.x >> 6) * WCAP;

    // ---- XCD self-registration (counters host-zeroed) ----
    if (threadIdx.x == 0) {
        u32 x;
        asm volatile("s_getreg_b32 %0, hwreg(HW_REG_XCC_ID)" : "=s"(x));
        x &= 15;
        s_xcd = (int)x;
        s_rank = atomicAdd(&xcd_cnt[x], 1);   // device scope -> IF
    }

    // ---- P0: zero counters + zero dummy pads (agent -> IF) ----
    {
        u32* zp = (u32*)row_cnt;   // row_cnt..col_cnt contiguous, 96 KB
        for (int t = tid; t < ZERO_WORDS; t += NTH) agent_st32(&zp[t], 0u);
        if (tid < 32) {            // bel pads: slice g, dummy vi=16384
            int g = tid >> 2, j = tid & 3;
            agent_stf(&bel_x[(size_t)g * BEL_SL + V_NUM * 4 + j], 0.0f);
        } else if (tid < 64) {     // cms pads: slice g, dummy ci=8192
            int g = (tid - 32) >> 2, j = tid & 3;
            agent_stf(&cms_x[(size_t)g * CMS_SL + C_NUM * 4 + j], 0.0f);
        }
    }

    // ---- P1a: stream dense H, compact nonzeros into per-wave LDS list ----
    int wave_cnt;
    {
        const float4* Hv = (const float4*)H;
        const u64 ltmask = (1ull << lane) - 1ull;
        int wb = 0;
        int ta = tid;
        int tb = tid + 2 * NTH;
        float4 a0 = Hv[ta], a1 = Hv[ta + NTH];
        float4 b0 = Hv[tb], b1 = Hv[tb + NTH];
#pragma unroll 1
        for (int itn = 0; itn < 64; ++itn) {
            int tc = tb + 2 * NTH;
            float4 p0, p1;
            if (itn < 62) { p0 = Hv[tc]; p1 = Hv[tc + NTH]; }
            float vals[8] = {a0.x, a0.y, a0.z, a0.w, a1.x, a1.y, a1.z, a1.w};
#pragma unroll
            for (int k = 0; k < 8; ++k) {
                bool nz = vals[k] != 0.0f;
                u64 bb = __ballot(nz);
                if (bb) {
                    if (nz) {
                        int ee = (k < 4) ? (ta * 4 + k)
                                         : ((ta + NTH) * 4 + (k - 4));
                        int off = wb + (int)__popcll(bb & ltmask);
                        if (off < WCAP) wl[off] = (u32)ee;
                    }
                    wb += (int)__popcll(bb);
                }
            }
            a0 = b0; a1 = b1; b0 = p0; b1 = p1; ta = tb; tb = tc;
        }
        wave_cnt = wb < WCAP ? wb : WCAP;
    }
    // Barrier: counters/pads zeroed everywhere; registrations complete.
    grid_barrier(bars, 0);

    // ---- P1b: CSR insertion from LDS edge lists (~33 edges/wave) ----
    {
        for (int e = lane; e < wave_cnt; e += 64) {
            u32 ee = wl[e];
            int c = (int)(ee >> 14);             // V = 2^14
            int v = (int)(ee & (V_NUM - 1));
            int rs = atomicAdd(&row_cnt[c], 1);  // device-scope -> IF
            if (rs < RW) agent_st16(&row_idx[(size_t)c * RW + rs], (u16)v);
            int cs = atomicAdd(&col_cnt[v], 1);
            if (cs < CW) agent_st16(&col_idx[(size_t)v * CW + cs], (u16)c);
        }
    }
    grid_barrier(bars, 1);

    // ---- group assignment: physical XCD if balanced, else virtual ----
    int my_xcd = s_xcd, my_rank = s_rank;   // visible post-barrier
    bool balanced = true;
#pragma unroll
    for (int g = 0; g < 8; ++g) balanced &= (agent_ldi(&xcd_cnt[g]) == 32);

    const float wvc = w_vc_p[0];
    const float wcv = w_cv_p[0];
    const float d   = damp_p[0];

    if (balanced) {
        decode_tail<true>(my_xcd, my_rank, synd, llr, row_cnt, col_cnt,
                          row_idx, col_idx, bel_x, cms_x, bars, out,
                          ls_row, ls_col, wvc, wcv, d);
    } else {
        decode_tail<false>((int)(blockIdx.x >> 5), (int)(blockIdx.x & 31),
                           synd, llr, row_cnt, col_cnt,
                           row_idx, col_idx, bel_x, cms_x, bars, out,
                           ls_row, ls_col, wvc, wcv, d);
    }
}

extern "C" void kernel_launch(void* const* d_in, const int* in_sizes, int n_in,
                              void* d_out, int out_size, void* d_ws, size_t ws_size,
                              hipStream_t stream) {
    const float* synd = (const float*)d_in[0];   // (B, C)
    const float* H    = (const float*)d_in[1];   // (C, V)
    const float* llr  = (const float*)d_in[2];   // (B, V)
    const float* w_vc = (const float*)d_in[3];
    const float* w_cv = (const float*)d_in[4];
    const float* damp = (const float*)d_in[5];
    float* out = (float*)d_out;

    char* ws = (char*)d_ws;
    size_t off = 0;
    int* row_cnt = (int*)(ws + off); off += (size_t)C_NUM * 4;        // 32 KB
    int* col_cnt = (int*)(ws + off); off += (size_t)V_NUM * 4;        // 64 KB
    u16* row_idx = (u16*)(ws + off); off += (size_t)C_NUM * RW * 2;   // 1 MB
    u16* col_idx = (u16*)(ws + off); off += (size_t)V_NUM * CW * 2;   // 1 MB
    float* bel_x = (float*)(ws + off); off += (size_t)8 * BEL_SL * 4; // 2.1 MB
    float* cms_x = (float*)(ws + off); off += (size_t)8 * CMS_SL * 4; // 1.05 MB
    u32* bars  = (u32*)(ws + off); off += (size_t)NBAR * 8 * BAR_STRIDE * 4; // 64 KB
    int* xcd_cnt = (int*)(ws + off); off += 64;                       // 16 ints

    // bars + xcd_cnt are contiguous: one memset covers both
    hipMemsetAsync(bars, 0, (size_t)NBAR * 8 * BAR_STRIDE * 4 + 64, stream);

    void* args[] = {
        (void*)&H, (void*)&synd, (void*)&llr,
        (void*)&w_vc, (void*)&w_cv, (void*)&damp,
        (void*)&row_cnt, (void*)&col_cnt, (void*)&row_idx, (void*)&col_idx,
        (void*)&bel_x, (void*)&cms_x, (void*)&bars, (void*)&xcd_cnt,
        (void*)&out
    };
    hipLaunchCooperativeKernel((const void*)bp_fused,
                               dim3(NBLK), dim3(NTHR), args, 0, stream);
}